// Round 1
// baseline (1543.078 us; speedup 1.0000x reference)
//
#include <hip/hip_runtime.h>
#include <math.h>

#define NN 2048
#define HID 128
#define HID2 64
#define NP ((NN*(NN-1))/2)   // 2096128

// Kernel 1: per node row, fused h = relu(X@Wt + bt); A = h@W1[:128] + b1; B = h@W1[128:]
__global__ __launch_bounds__(128) void precompute_AB(
    const float* __restrict__ X, const float* __restrict__ Wt, const float* __restrict__ bt,
    const float* __restrict__ W1, const float* __restrict__ b1,
    float* __restrict__ A, float* __restrict__ B)
{
    __shared__ float x_s[HID];
    __shared__ float h_s[HID];
    const int row = blockIdx.x;
    const int c = threadIdx.x;
    x_s[c] = X[row*HID + c];
    __syncthreads();
    float hc = bt[c];
    #pragma unroll 8
    for (int k = 0; k < HID; ++k) hc = fmaf(x_s[k], Wt[k*HID + c], hc);
    h_s[c] = fmaxf(hc, 0.f);
    __syncthreads();
    float a = b1[c];
    float bsum = 0.f;
    #pragma unroll 8
    for (int k = 0; k < HID; ++k) {
        float hk = h_s[k];
        a    = fmaf(hk, W1[k*HID + c], a);
        bsum = fmaf(hk, W1[(HID + k)*HID + c], bsum);
    }
    A[row*HID + c] = a;
    B[row*HID + c] = bsum;
}

// Kernel 2: one thread per (i,j) pair; z = A[i]+B[j]; LN; relu; @W2; relu; @W3; sigmoid
__global__ __launch_bounds__(256) void pairs_kernel(
    const float* __restrict__ A, const float* __restrict__ B,
    const float* __restrict__ ln_g, const float* __restrict__ ln_b,
    const float* __restrict__ W2, const float* __restrict__ b2,
    const float* __restrict__ W3, const float* __restrict__ b3,
    float* __restrict__ out)
{
    __shared__ float a_s[HID];
    const int i = blockIdx.y;
    const int j = blockIdx.x * 256 + threadIdx.x;
    if (threadIdx.x < HID) a_s[threadIdx.x] = A[i*HID + threadIdx.x];
    __syncthreads();

    float* probs = out;
    float* pi    = out + NP;
    float* adj   = out + 3*(size_t)NP;

    if (j == i) {
        adj[(size_t)i*NN + i] = 0.f;   // diagonal
    }
    if (j <= i || j >= NN) return;

    const float* __restrict__ Brow = B + (size_t)j * HID;

    // pass 1: LN statistics of z = A[i] + B[j]
    float s1 = 0.f, s2 = 0.f;
    #pragma unroll 8
    for (int k = 0; k < HID; ++k) {
        float z = a_s[k] + Brow[k];
        s1 += z;
        s2 = fmaf(z, z, s2);
    }
    const float mu   = s1 * (1.f/HID);
    const float var  = s2 * (1.f/HID) - mu*mu;
    const float rstd = rsqrtf(var + 1e-5f);

    // pass 2: zn = relu(LN(z));  acc = zn @ W2 + b2   (W2 reads are wave-uniform -> SGPR)
    float acc[HID2];
    #pragma unroll
    for (int c = 0; c < HID2; ++c) acc[c] = b2[c];
    for (int k = 0; k < HID; ++k) {
        float z  = a_s[k] + Brow[k];
        float zn = fmaxf(fmaf((z - mu) * rstd, ln_g[k], ln_b[k]), 0.f);
        #pragma unroll
        for (int c = 0; c < HID2; ++c) acc[c] = fmaf(zn, W2[k*HID2 + c], acc[c]);
    }

    float logit = b3[0];
    #pragma unroll
    for (int c = 0; c < HID2; ++c) logit = fmaf(fmaxf(acc[c], 0.f), W3[c], logit);

    const float p = 1.f / (1.f + __expf(-logit));

    const int kpair = i*(NN-1) - (i*(i-1))/2 + (j - i - 1);
    probs[kpair]    = p;
    pi[kpair]       = (float)i;
    pi[NP + kpair]  = (float)j;
    adj[(size_t)i*NN + j] = p;
    adj[(size_t)j*NN + i] = p;
}

extern "C" void kernel_launch(void* const* d_in, const int* in_sizes, int n_in,
                              void* d_out, int out_size, void* d_ws, size_t ws_size,
                              hipStream_t stream) {
    const float* X    = (const float*)d_in[0];
    const float* Wt   = (const float*)d_in[1];
    const float* bt   = (const float*)d_in[2];
    const float* W1   = (const float*)d_in[3];
    const float* b1   = (const float*)d_in[4];
    const float* ln_g = (const float*)d_in[5];
    const float* ln_b = (const float*)d_in[6];
    const float* W2   = (const float*)d_in[7];
    const float* b2   = (const float*)d_in[8];
    const float* W3   = (const float*)d_in[9];
    const float* b3   = (const float*)d_in[10];
    float* out = (float*)d_out;

    float* A = (float*)d_ws;                  // [2048][128]
    float* B = A + (size_t)NN * HID;          // [2048][128]

    precompute_AB<<<NN, HID, 0, stream>>>(X, Wt, bt, W1, b1, A, B);
    pairs_kernel<<<dim3(NN/256, NN), 256, 0, stream>>>(A, B, ln_g, ln_b, W2, b2, W3, b3, out);
}